// Round 1
// baseline (1412.472 us; speedup 1.0000x reference)
//
#include <hip/hip_runtime.h>
#include <math.h>

#define DM 2048      // model dim
#define NT 16384     // tokens = B*S
#define KD 2048      // GEMM K
#define ND 2048      // GEMM N

typedef __bf16 bf16x8 __attribute__((ext_vector_type(8)));
typedef float  f32x4  __attribute__((ext_vector_type(4)));

__device__ __forceinline__ void gld_lds16(const void* g, void* l) {
  __builtin_amdgcn_global_load_lds(
      (const __attribute__((address_space(1))) unsigned int*)g,
      (__attribute__((address_space(3))) unsigned int*)l, 16, 0, 0);
}

// ---------------- cast fp32 -> bf16 (vectorized) ----------------
__global__ __launch_bounds__(256) void k_cast(const float* __restrict__ x,
                                              __bf16* __restrict__ y) {
  const size_t i = ((size_t)blockIdx.x * 256 + threadIdx.x) * 8;
  const float4 a = *(const float4*)(x + i);
  const float4 b = *(const float4*)(x + i + 4);
  bf16x8 o;
  o[0]=(__bf16)a.x; o[1]=(__bf16)a.y; o[2]=(__bf16)a.z; o[3]=(__bf16)a.w;
  o[4]=(__bf16)b.x; o[5]=(__bf16)b.y; o[6]=(__bf16)b.z; o[7]=(__bf16)b.w;
  *(bf16x8*)(y + i) = o;
}

// -------- transpose+cast: W (KDxND fp32 row-major) -> Wt (NDxKD bf16) --------
__global__ __launch_bounds__(256) void k_transpose(const float* __restrict__ W,
                                                   __bf16* __restrict__ Wt) {
  __shared__ float t[32][33];
  const int tx = threadIdx.x, ty = threadIdx.y;
  const int n  = blockIdx.x * 32 + tx;
  const int k0 = blockIdx.y * 32;
  #pragma unroll
  for (int j = 0; j < 32; j += 8) t[ty + j][tx] = W[(size_t)(k0 + ty + j) * ND + n];
  __syncthreads();
  const int kk = k0 + tx;
  const int n0 = blockIdx.x * 32;
  #pragma unroll
  for (int j = 0; j < 32; j += 8)
    Wt[(size_t)(n0 + ty + j) * KD + kk] = (__bf16)t[tx][ty + j];
}

// ---------------- bf16 MFMA GEMM, m97 structure ----------------
// A: M x K bf16 row-major.  Bt: N x K bf16 row-major (B transposed).
// mode 0: out = bf16(acc + bias)                       -> outb
// mode 1: out = bf16(gelu(acc + bias))                 -> outb
// mode 2: out = acc + bias + resf (fp32 residual)      -> outf
// mode 3: out = acc + bias + resb (bf16 residual)      -> outf
__global__ __launch_bounds__(256, 2) void k_gemm(
    const __bf16* __restrict__ A, const __bf16* __restrict__ Bt,
    const float* __restrict__ bias, const int mode,
    __bf16* __restrict__ outb, const float* __restrict__ resf,
    const __bf16* __restrict__ resb, float* __restrict__ outf) {
  __shared__ __bf16 As[128 * 32];
  __shared__ __bf16 Bs[128 * 32];
  const int tid  = threadIdx.x;
  const int wave = tid >> 6, lane = tid & 63;
  const int quad = lane >> 4, r16 = lane & 15;
  const int m0 = blockIdx.x * 128, n0 = blockIdx.y * 128;
  const int wm = (wave >> 1) * 64, wn = (wave & 1) * 64;

  // staging: element e in tile -> row e>>5, col e&31; lane order == LDS order
  const int srow = tid >> 2;
  const int scol = (tid & 3) * 8;
  const __bf16* Ap0 = A  + (size_t)(m0 + srow) * KD + scol;
  const __bf16* Ap1 = A  + (size_t)(m0 + 64 + srow) * KD + scol;
  const __bf16* Bp0 = Bt + (size_t)(n0 + srow) * KD + scol;
  const __bf16* Bp1 = Bt + (size_t)(n0 + 64 + srow) * KD + scol;
  __bf16* AsW0 = &As[wave * 512];
  __bf16* AsW1 = &As[2048 + wave * 512];
  __bf16* BsW0 = &Bs[wave * 512];
  __bf16* BsW1 = &Bs[2048 + wave * 512];

  f32x4 acc[4][4] = {};

  for (int k0 = 0; k0 < KD; k0 += 32) {
    gld_lds16(Ap0 + k0, AsW0);
    gld_lds16(Ap1 + k0, AsW1);
    gld_lds16(Bp0 + k0, BsW0);
    gld_lds16(Bp1 + k0, BsW1);
    __syncthreads();
    bf16x8 af[4], bfr[4];
    #pragma unroll
    for (int mi = 0; mi < 4; mi++)
      af[mi] = *(const bf16x8*)&As[(wm + mi * 16 + r16) * 32 + quad * 8];
    #pragma unroll
    for (int ni = 0; ni < 4; ni++)
      bfr[ni] = *(const bf16x8*)&Bs[(wn + ni * 16 + r16) * 32 + quad * 8];
    #pragma unroll
    for (int mi = 0; mi < 4; mi++)
      #pragma unroll
      for (int ni = 0; ni < 4; ni++)
        acc[mi][ni] = __builtin_amdgcn_mfma_f32_16x16x32_bf16(af[mi], bfr[ni], acc[mi][ni], 0, 0, 0);
    __syncthreads();
  }

  // epilogue: C/D layout col=lane&15, row=(lane>>4)*4+reg
  #pragma unroll
  for (int ni = 0; ni < 4; ni++) {
    const int gn = n0 + wn + ni * 16 + r16;
    const float bv = bias[gn];
    #pragma unroll
    for (int mi = 0; mi < 4; mi++) {
      const int gm = m0 + wm + mi * 16 + quad * 4;
      if (mode == 0) {
        #pragma unroll
        for (int r = 0; r < 4; r++)
          outb[(size_t)(gm + r) * ND + gn] = (__bf16)(acc[mi][ni][r] + bv);
      } else if (mode == 1) {
        #pragma unroll
        for (int r = 0; r < 4; r++) {
          float v = acc[mi][ni][r] + bv;
          float gel = 0.5f * v * (1.0f + erff(v * 0.70710678118654752f));
          outb[(size_t)(gm + r) * ND + gn] = (__bf16)gel;
        }
      } else if (mode == 2) {
        #pragma unroll
        for (int r = 0; r < 4; r++) {
          const size_t o = (size_t)(gm + r) * ND + gn;
          outf[o] = acc[mi][ni][r] + bv + resf[o];
        }
      } else {
        #pragma unroll
        for (int r = 0; r < 4; r++) {
          const size_t o = (size_t)(gm + r) * ND + gn;
          outf[o] = acc[mi][ni][r] + bv + (float)resb[o];
        }
      }
    }
  }
}

// -------- per-token head-attention + residual + LN1 (one block per token) --------
__global__ __launch_bounds__(256) void k_attn_ln1(
    const __bf16* __restrict__ Q, const __bf16* __restrict__ Kq,
    const __bf16* __restrict__ V, const float* __restrict__ X,
    const float* __restrict__ g1, const float* __restrict__ be1,
    float* __restrict__ X1, __bf16* __restrict__ X1b, const int use_f32) {
  __shared__ float qs[16 * 132];  // stride 132 breaks 16-way bank conflicts
  __shared__ float ks[16 * 132];
  __shared__ float vs[16 * 132];
  __shared__ float p[256];
  __shared__ float red[8];
  const int tid = threadIdx.x;
  const size_t base = (size_t)blockIdx.x * DM;
  const int e0 = tid * 8;

  {  // load q,k,v rows -> LDS fp32
    const int row = e0 >> 7, c0 = e0 & 127;
    bf16x8 qv = *(const bf16x8*)(Q + base + e0);
    bf16x8 kv = *(const bf16x8*)(Kq + base + e0);
    bf16x8 vv = *(const bf16x8*)(V + base + e0);
    #pragma unroll
    for (int j = 0; j < 8; j++) {
      qs[row * 132 + c0 + j] = (float)qv[j];
      ks[row * 132 + c0 + j] = (float)kv[j];
      vs[row * 132 + c0 + j] = (float)vv[j];
    }
  }
  __syncthreads();

  {  // scores + softmax over t (16 lanes per head, contiguous in a wave)
    const int h = tid >> 4, t = tid & 15;
    const float* qp = &qs[h * 132];
    const float* kp = &ks[t * 132];
    float s = 0.f;
    #pragma unroll
    for (int d = 0; d < 128; d++) s += qp[d] * kp[d];
    s *= 0.08838834764831845f;  // 1/sqrt(128)
    float mx = s;
    #pragma unroll
    for (int off = 8; off; off >>= 1) mx = fmaxf(mx, __shfl_xor(mx, off, 16));
    const float e = expf(s - mx);
    float sum = e;
    #pragma unroll
    for (int off = 8; off; off >>= 1) sum += __shfl_xor(sum, off, 16);
    p[tid] = e / sum;
  }
  __syncthreads();

  // y = att @ v ; z = X + y ; LN partials
  float zloc[8];
  float zs = 0.f, zq = 0.f;
  {
    const float4 x1 = *(const float4*)(X + base + e0);
    const float4 x2 = *(const float4*)(X + base + e0 + 4);
    const float xr[8] = {x1.x, x1.y, x1.z, x1.w, x2.x, x2.y, x2.z, x2.w};
    const int hh = e0 >> 7;
    const int d0 = e0 & 127;
    const float* pp = &p[hh * 16];
    #pragma unroll
    for (int j = 0; j < 8; j++) {
      float y = 0.f;
      #pragma unroll
      for (int t2 = 0; t2 < 16; t2++) y += pp[t2] * vs[t2 * 132 + d0 + j];
      const float z = xr[j] + y;
      zloc[j] = z; zs += z; zq += z * z;
    }
  }
  #pragma unroll
  for (int off = 32; off; off >>= 1) {
    zs += __shfl_xor(zs, off, 64);
    zq += __shfl_xor(zq, off, 64);
  }
  const int wave = tid >> 6, lane = tid & 63;
  if (lane == 0) { red[wave] = zs; red[4 + wave] = zq; }
  __syncthreads();
  zs = red[0] + red[1] + red[2] + red[3];
  zq = red[4] + red[5] + red[6] + red[7];
  const float mean = zs * (1.f / DM);
  const float var = zq * (1.f / DM) - mean * mean;
  const float rstd = rsqrtf(var + 1e-5f);
  {
    float o[8];
    #pragma unroll
    for (int j = 0; j < 8; j++)
      o[j] = (zloc[j] - mean) * rstd * g1[e0 + j] + be1[e0 + j];
    if (use_f32) {
      *(float4*)(X1 + base + e0)     = make_float4(o[0], o[1], o[2], o[3]);
      *(float4*)(X1 + base + e0 + 4) = make_float4(o[4], o[5], o[6], o[7]);
    }
    bf16x8 ob;
    #pragma unroll
    for (int j = 0; j < 8; j++) ob[j] = (__bf16)o[j];
    *(bf16x8*)(X1b + base + e0) = ob;
  }
}

// ---------------- final LN2 (one block per token) ----------------
__global__ __launch_bounds__(256) void k_ln2(const float* __restrict__ Z,
                                             const float* __restrict__ g,
                                             const float* __restrict__ be,
                                             float* __restrict__ out) {
  __shared__ float red[8];
  const int tid = threadIdx.x;
  const size_t base = (size_t)blockIdx.x * DM;
  const int e0 = tid * 8;
  const float4 a = *(const float4*)(Z + base + e0);
  const float4 b = *(const float4*)(Z + base + e0 + 4);
  float z[8] = {a.x, a.y, a.z, a.w, b.x, b.y, b.z, b.w};
  float zs = 0.f, zq = 0.f;
  #pragma unroll
  for (int j = 0; j < 8; j++) { zs += z[j]; zq += z[j] * z[j]; }
  #pragma unroll
  for (int off = 32; off; off >>= 1) {
    zs += __shfl_xor(zs, off, 64);
    zq += __shfl_xor(zq, off, 64);
  }
  const int wave = tid >> 6, lane = tid & 63;
  if (lane == 0) { red[wave] = zs; red[4 + wave] = zq; }
  __syncthreads();
  zs = red[0] + red[1] + red[2] + red[3];
  zq = red[4] + red[5] + red[6] + red[7];
  const float mean = zs * (1.f / DM);
  const float var = zq * (1.f / DM) - mean * mean;
  const float rstd = rsqrtf(var + 1e-5f);
  float o[8];
  #pragma unroll
  for (int j = 0; j < 8; j++)
    o[j] = (z[j] - mean) * rstd * g[e0 + j] + be[e0 + j];
  *(float4*)(out + base + e0)     = make_float4(o[0], o[1], o[2], o[3]);
  *(float4*)(out + base + e0 + 4) = make_float4(o[4], o[5], o[6], o[7]);
}

extern "C" void kernel_launch(void* const* d_in, const int* in_sizes, int n_in,
                              void* d_out, int out_size, void* d_ws, size_t ws_size,
                              hipStream_t stream) {
  const float* X   = (const float*)d_in[0];
  const float* Wq  = (const float*)d_in[1];
  const float* bq  = (const float*)d_in[2];
  const float* Wk  = (const float*)d_in[3];
  const float* bk  = (const float*)d_in[4];
  const float* Wv  = (const float*)d_in[5];
  const float* bv  = (const float*)d_in[6];
  const float* g1  = (const float*)d_in[7];
  const float* be1 = (const float*)d_in[8];
  const float* W1  = (const float*)d_in[9];
  const float* b1  = (const float*)d_in[10];
  const float* W2  = (const float*)d_in[11];
  const float* b2  = (const float*)d_in[12];
  const float* g2  = (const float*)d_in[13];
  const float* be2 = (const float*)d_in[14];
  float* out = (float*)d_out;

  char* ws = (char*)d_ws;
  size_t off = 0;
  auto alloc = [&](size_t b) -> char* {
    char* p = ws + off;
    off += (b + 255) & ~(size_t)255;
    return p;
  };
  const size_t EL = (size_t)NT * DM;
  __bf16* Xb  = (__bf16*)alloc(EL * 2);
  __bf16* Wqt = (__bf16*)alloc((size_t)ND * KD * 2);
  __bf16* Wkt = (__bf16*)alloc((size_t)ND * KD * 2);
  __bf16* Wvt = (__bf16*)alloc((size_t)ND * KD * 2);
  __bf16* W1t = (__bf16*)alloc((size_t)ND * KD * 2);
  __bf16* W2t = (__bf16*)alloc((size_t)ND * KD * 2);
  __bf16* Qb  = (__bf16*)alloc(EL * 2);
  __bf16* Kb  = (__bf16*)alloc(EL * 2);
  __bf16* Vb  = (__bf16*)alloc(EL * 2);
  __bf16* X1b = (__bf16*)alloc(EL * 2);
  // fp32 X1 residual if workspace allows; else fall back to bf16 residual
  const int use_f32 = (ws_size >= off + EL * 4) ? 1 : 0;
  float* X1 = nullptr;
  if (use_f32) X1 = (float*)alloc(EL * 4);
  __bf16* Hb = Xb;          // h reuses Xb (dead after QKV GEMMs)
  float*  Z  = (float*)Qb;  // Z reuses Qb+Kb (dead after attention)

  k_cast<<<dim3(NT * DM / 2048), dim3(256), 0, stream>>>(X, Xb);
  dim3 tb(32, 8), tg(64, 64);
  k_transpose<<<tg, tb, 0, stream>>>(Wq, Wqt);
  k_transpose<<<tg, tb, 0, stream>>>(Wk, Wkt);
  k_transpose<<<tg, tb, 0, stream>>>(Wv, Wvt);
  k_transpose<<<tg, tb, 0, stream>>>(W1, W1t);
  k_transpose<<<tg, tb, 0, stream>>>(W2, W2t);
  dim3 gg(NT / 128, ND / 128);
  k_gemm<<<gg, dim3(256), 0, stream>>>(Xb, Wqt, bq, 0, Qb, nullptr, nullptr, nullptr);
  k_gemm<<<gg, dim3(256), 0, stream>>>(Xb, Wkt, bk, 0, Kb, nullptr, nullptr, nullptr);
  k_gemm<<<gg, dim3(256), 0, stream>>>(Xb, Wvt, bv, 0, Vb, nullptr, nullptr, nullptr);
  k_attn_ln1<<<dim3(NT), dim3(256), 0, stream>>>(Qb, Kb, Vb, X, g1, be1, X1, X1b, use_f32);
  k_gemm<<<gg, dim3(256), 0, stream>>>(X1b, W1t, b1, 1, Hb, nullptr, nullptr, nullptr);
  k_gemm<<<gg, dim3(256), 0, stream>>>(Hb, W2t, b2, use_f32 ? 2 : 3, nullptr, X1, X1b, Z);
  k_ln2<<<dim3(NT), dim3(256), 0, stream>>>(Z, g2, be2, out);
}

// Round 2
// 1381.714 us; speedup vs baseline: 1.0223x; 1.0223x over previous
//
#include <hip/hip_runtime.h>
#include <math.h>

#define DM 2048      // model dim
#define NT 16384     // tokens = B*S
#define KD 2048      // GEMM K

typedef __bf16 bf16x8 __attribute__((ext_vector_type(8)));
typedef float  f32x4  __attribute__((ext_vector_type(4)));

__device__ __forceinline__ void gld_lds16(const void* g, void* l) {
  __builtin_amdgcn_global_load_lds(
      (const __attribute__((address_space(1))) unsigned int*)g,
      (__attribute__((address_space(3))) unsigned int*)l, 16, 0, 0);
}

// ---------------- cast fp32 -> bf16 (vectorized) ----------------
__global__ __launch_bounds__(256) void k_cast(const float* __restrict__ x,
                                              __bf16* __restrict__ y) {
  const size_t i = ((size_t)blockIdx.x * 256 + threadIdx.x) * 8;
  const float4 a = *(const float4*)(x + i);
  const float4 b = *(const float4*)(x + i + 4);
  bf16x8 o;
  o[0]=(__bf16)a.x; o[1]=(__bf16)a.y; o[2]=(__bf16)a.z; o[3]=(__bf16)a.w;
  o[4]=(__bf16)b.x; o[5]=(__bf16)b.y; o[6]=(__bf16)b.z; o[7]=(__bf16)b.w;
  *(bf16x8*)(y + i) = o;
}

// -------- transpose+cast: W (KDxN fp32 row-major, N=2048) -> Wt (N x KD bf16) --------
__global__ __launch_bounds__(256) void k_transpose(const float* __restrict__ W,
                                                   __bf16* __restrict__ Wt) {
  __shared__ float t[32][33];
  const int tx = threadIdx.x, ty = threadIdx.y;
  const int n  = blockIdx.x * 32 + tx;
  const int k0 = blockIdx.y * 32;
  #pragma unroll
  for (int j = 0; j < 32; j += 8) t[ty + j][tx] = W[(size_t)(k0 + ty + j) * DM + n];
  __syncthreads();
  const int kk = k0 + tx;
  const int n0 = blockIdx.x * 32;
  #pragma unroll
  for (int j = 0; j < 32; j += 8)
    Wt[(size_t)(n0 + ty + j) * KD + kk] = (__bf16)t[tx][ty + j];
}

// -------- concat 3 bias vectors (2048 each) into one 6144 --------
__global__ __launch_bounds__(256) void k_bias3(const float* __restrict__ a,
                                               const float* __restrict__ b,
                                               const float* __restrict__ c,
                                               float* __restrict__ o) {
  const int i = blockIdx.x * 256 + threadIdx.x;
  o[i] = (i < 2048) ? a[i] : ((i < 4096) ? b[i - 2048] : c[i - 4096]);
}

// ---------------- bf16 MFMA GEMM, m97 structure + N-fastest swizzle ----------------
// A: M x KD bf16 row-major.  Bt: N x KD bf16 row-major (B transposed).
// 1-D grid, bid -> (mt = bid/ntile_n, nt = bid%ntile_n): consecutive blocks share
// the A row-tile (L2/L3 reuse), sweep B columns (B stays L3-resident).
// mode 0: out = bf16(acc + bias)                      -> outb (LDS-coalesced stores)
// mode 1: out = bf16(gelu(acc + bias))                -> outb (LDS-coalesced stores)
// mode 2: out = acc + bias + resf (fp32 residual)     -> outf
// mode 3: out = acc + bias + resb (bf16 residual)     -> outf
__global__ __launch_bounds__(256, 2) void k_gemm(
    const __bf16* __restrict__ A, const __bf16* __restrict__ Bt,
    const float* __restrict__ bias, const int mode, const int ntile_n,
    const int NS,
    __bf16* __restrict__ outb, const float* __restrict__ resf,
    const __bf16* __restrict__ resb, float* __restrict__ outf) {
  __shared__ __bf16 As[128 * 32];
  __shared__ __bf16 Bs[128 * 32];
  const int tid  = threadIdx.x;
  const int wave = tid >> 6, lane = tid & 63;
  const int quad = lane >> 4, r16 = lane & 15;
  const int bid = blockIdx.x;
  const int m0 = (bid / ntile_n) * 128;
  const int n0 = (bid % ntile_n) * 128;
  const int wm = (wave >> 1) * 64, wn = (wave & 1) * 64;

  // staging: lane order == LDS order (global_load_lds is wave-uniform base + lane*16)
  const int srow = tid >> 2;
  const int scol = (tid & 3) * 8;
  const __bf16* Ap0 = A  + (size_t)(m0 + srow) * KD + scol;
  const __bf16* Ap1 = A  + (size_t)(m0 + 64 + srow) * KD + scol;
  const __bf16* Bp0 = Bt + (size_t)(n0 + srow) * KD + scol;
  const __bf16* Bp1 = Bt + (size_t)(n0 + 64 + srow) * KD + scol;
  __bf16* AsW0 = &As[wave * 512];
  __bf16* AsW1 = &As[2048 + wave * 512];
  __bf16* BsW0 = &Bs[wave * 512];
  __bf16* BsW1 = &Bs[2048 + wave * 512];

  f32x4 acc[4][4] = {};

  for (int k0 = 0; k0 < KD; k0 += 32) {
    gld_lds16(Ap0 + k0, AsW0);
    gld_lds16(Ap1 + k0, AsW1);
    gld_lds16(Bp0 + k0, BsW0);
    gld_lds16(Bp1 + k0, BsW1);
    __syncthreads();
    bf16x8 af[4], bfr[4];
    #pragma unroll
    for (int mi = 0; mi < 4; mi++)
      af[mi] = *(const bf16x8*)&As[(wm + mi * 16 + r16) * 32 + quad * 8];
    #pragma unroll
    for (int ni = 0; ni < 4; ni++)
      bfr[ni] = *(const bf16x8*)&Bs[(wn + ni * 16 + r16) * 32 + quad * 8];
    #pragma unroll
    for (int mi = 0; mi < 4; mi++)
      #pragma unroll
      for (int ni = 0; ni < 4; ni++)
        acc[mi][ni] = __builtin_amdgcn_mfma_f32_16x16x32_bf16(af[mi], bfr[ni], acc[mi][ni], 0, 0, 0);
    __syncthreads();
  }

  // epilogue: C/D layout col=lane&15, row=(lane>>4)*4+reg
  if (mode <= 1) {
    // bf16 out: transpose through per-wave LDS chunk (As/Bs dead after last sync)
    // -> 16B/lane fully-coalesced global stores (kills write amplification)
    __bf16* eb = (wave < 2) ? &As[wave * 2048] : &Bs[(wave - 2) * 2048];  // 64x32 bf16
    #pragma unroll
    for (int half = 0; half < 2; half++) {
      #pragma unroll
      for (int nj = 0; nj < 2; nj++) {
        const int ni = half * 2 + nj;
        const int gn = n0 + wn + ni * 16 + r16;
        const float bv = bias[gn];
        #pragma unroll
        for (int mi = 0; mi < 4; mi++) {
          #pragma unroll
          for (int r = 0; r < 4; r++) {
            float v = acc[mi][ni][r] + bv;
            if (mode == 1) v = 0.5f * v * (1.0f + erff(v * 0.70710678118654752f));
            eb[(mi * 16 + quad * 4 + r) * 32 + nj * 16 + r16] = (__bf16)v;
          }
        }
      }
      // same-wave LDS write->read: compiler inserts lgkmcnt waits; no barrier needed
      #pragma unroll
      for (int rd = 0; rd < 4; rd++) {
        const int row = rd * 16 + (lane >> 2);
        const int c0 = (lane & 3) * 8;
        bf16x8 vv = *(const bf16x8*)&eb[row * 32 + c0];
        *(bf16x8*)(outb + (size_t)(m0 + wm + row) * NS + n0 + wn + half * 32 + c0) = vv;
      }
    }
  } else {
    // fp32 out (+residual): 16 lanes x 4B = full 64B lines already
    #pragma unroll
    for (int ni = 0; ni < 4; ni++) {
      const int gn = n0 + wn + ni * 16 + r16;
      const float bv = bias[gn];
      #pragma unroll
      for (int mi = 0; mi < 4; mi++) {
        const int gm = m0 + wm + mi * 16 + quad * 4;
        if (mode == 2) {
          #pragma unroll
          for (int r = 0; r < 4; r++) {
            const size_t o = (size_t)(gm + r) * NS + gn;
            outf[o] = acc[mi][ni][r] + bv + resf[o];
          }
        } else {
          #pragma unroll
          for (int r = 0; r < 4; r++) {
            const size_t o = (size_t)(gm + r) * NS + gn;
            outf[o] = acc[mi][ni][r] + bv + (float)resb[o];
          }
        }
      }
    }
  }
}

// -------- per-token head-attention + residual + LN1 (one block per token) --------
// QKV: NT x 6144 bf16 (q | k | v per token row)
__global__ __launch_bounds__(256) void k_attn_ln1(
    const __bf16* __restrict__ QKV, const float* __restrict__ X,
    const float* __restrict__ g1, const float* __restrict__ be1,
    float* __restrict__ X1, __bf16* __restrict__ X1b, const int use_f32) {
  __shared__ float qs[16 * 132];  // stride 132 breaks 16-way bank conflicts
  __shared__ float ks[16 * 132];
  __shared__ float vs[16 * 132];
  __shared__ float p[256];
  __shared__ float red[8];
  const int tid = threadIdx.x;
  const size_t qbase = (size_t)blockIdx.x * 6144;
  const size_t base  = (size_t)blockIdx.x * DM;
  const int e0 = tid * 8;

  {  // load q,k,v rows -> LDS fp32
    const int row = e0 >> 7, c0 = e0 & 127;
    bf16x8 qv = *(const bf16x8*)(QKV + qbase + e0);
    bf16x8 kv = *(const bf16x8*)(QKV + qbase + 2048 + e0);
    bf16x8 vv = *(const bf16x8*)(QKV + qbase + 4096 + e0);
    #pragma unroll
    for (int j = 0; j < 8; j++) {
      qs[row * 132 + c0 + j] = (float)qv[j];
      ks[row * 132 + c0 + j] = (float)kv[j];
      vs[row * 132 + c0 + j] = (float)vv[j];
    }
  }
  __syncthreads();

  {  // scores + softmax over t (16 lanes per head)
    const int h = tid >> 4, t = tid & 15;
    const float* qp = &qs[h * 132];
    const float* kp = &ks[t * 132];
    float s = 0.f;
    #pragma unroll
    for (int d = 0; d < 128; d++) s += qp[d] * kp[d];
    s *= 0.08838834764831845f;  // 1/sqrt(128)
    float mx = s;
    #pragma unroll
    for (int off = 8; off; off >>= 1) mx = fmaxf(mx, __shfl_xor(mx, off, 16));
    const float e = expf(s - mx);
    float sum = e;
    #pragma unroll
    for (int off = 8; off; off >>= 1) sum += __shfl_xor(sum, off, 16);
    p[tid] = e / sum;
  }
  __syncthreads();

  // y = att @ v ; z = X + y ; LN partials
  float zloc[8];
  float zs = 0.f, zq = 0.f;
  {
    const float4 x1 = *(const float4*)(X + base + e0);
    const float4 x2 = *(const float4*)(X + base + e0 + 4);
    const float xr[8] = {x1.x, x1.y, x1.z, x1.w, x2.x, x2.y, x2.z, x2.w};
    const int hh = e0 >> 7;
    const int d0 = e0 & 127;
    const float* pp = &p[hh * 16];
    #pragma unroll
    for (int j = 0; j < 8; j++) {
      float y = 0.f;
      #pragma unroll
      for (int t2 = 0; t2 < 16; t2++) y += pp[t2] * vs[t2 * 132 + d0 + j];
      const float z = xr[j] + y;
      zloc[j] = z; zs += z; zq += z * z;
    }
  }
  #pragma unroll
  for (int off = 32; off; off >>= 1) {
    zs += __shfl_xor(zs, off, 64);
    zq += __shfl_xor(zq, off, 64);
  }
  const int wave = tid >> 6, lane = tid & 63;
  if (lane == 0) { red[wave] = zs; red[4 + wave] = zq; }
  __syncthreads();
  zs = red[0] + red[1] + red[2] + red[3];
  zq = red[4] + red[5] + red[6] + red[7];
  const float mean = zs * (1.f / DM);
  const float var = zq * (1.f / DM) - mean * mean;
  const float rstd = rsqrtf(var + 1e-5f);
  {
    float o[8];
    #pragma unroll
    for (int j = 0; j < 8; j++)
      o[j] = (zloc[j] - mean) * rstd * g1[e0 + j] + be1[e0 + j];
    if (use_f32) {
      *(float4*)(X1 + base + e0)     = make_float4(o[0], o[1], o[2], o[3]);
      *(float4*)(X1 + base + e0 + 4) = make_float4(o[4], o[5], o[6], o[7]);
    }
    bf16x8 ob;
    #pragma unroll
    for (int j = 0; j < 8; j++) ob[j] = (__bf16)o[j];
    *(bf16x8*)(X1b + base + e0) = ob;
  }
}

// ---------------- final LN2 (one block per token) ----------------
__global__ __launch_bounds__(256) void k_ln2(const float* __restrict__ Z,
                                             const float* __restrict__ g,
                                             const float* __restrict__ be,
                                             float* __restrict__ out) {
  __shared__ float red[8];
  const int tid = threadIdx.x;
  const size_t base = (size_t)blockIdx.x * DM;
  const int e0 = tid * 8;
  const float4 a = *(const float4*)(Z + base + e0);
  const float4 b = *(const float4*)(Z + base + e0 + 4);
  float z[8] = {a.x, a.y, a.z, a.w, b.x, b.y, b.z, b.w};
  float zs = 0.f, zq = 0.f;
  #pragma unroll
  for (int j = 0; j < 8; j++) { zs += z[j]; zq += z[j] * z[j]; }
  #pragma unroll
  for (int off = 32; off; off >>= 1) {
    zs += __shfl_xor(zs, off, 64);
    zq += __shfl_xor(zq, off, 64);
  }
  const int wave = tid >> 6, lane = tid & 63;
  if (lane == 0) { red[wave] = zs; red[4 + wave] = zq; }
  __syncthreads();
  zs = red[0] + red[1] + red[2] + red[3];
  zq = red[4] + red[5] + red[6] + red[7];
  const float mean = zs * (1.f / DM);
  const float var = zq * (1.f / DM) - mean * mean;
  const float rstd = rsqrtf(var + 1e-5f);
  float o[8];
  #pragma unroll
  for (int j = 0; j < 8; j++)
    o[j] = (z[j] - mean) * rstd * g[e0 + j] + be[e0 + j];
  *(float4*)(out + base + e0)     = make_float4(o[0], o[1], o[2], o[3]);
  *(float4*)(out + base + e0 + 4) = make_float4(o[4], o[5], o[6], o[7]);
}

extern "C" void kernel_launch(void* const* d_in, const int* in_sizes, int n_in,
                              void* d_out, int out_size, void* d_ws, size_t ws_size,
                              hipStream_t stream) {
  const float* X   = (const float*)d_in[0];
  const float* Wq  = (const float*)d_in[1];
  const float* bq  = (const float*)d_in[2];
  const float* Wk  = (const float*)d_in[3];
  const float* bk  = (const float*)d_in[4];
  const float* Wv  = (const float*)d_in[5];
  const float* bv  = (const float*)d_in[6];
  const float* g1  = (const float*)d_in[7];
  const float* be1 = (const float*)d_in[8];
  const float* W1  = (const float*)d_in[9];
  const float* b1  = (const float*)d_in[10];
  const float* W2  = (const float*)d_in[11];
  const float* b2  = (const float*)d_in[12];
  const float* g2  = (const float*)d_in[13];
  const float* be2 = (const float*)d_in[14];
  float* out = (float*)d_out;

  char* ws = (char*)d_ws;
  size_t off = 0;
  auto alloc = [&](size_t b) -> char* {
    char* p = ws + off;
    off += (b + 255) & ~(size_t)255;
    return p;
  };
  const size_t EL  = (size_t)NT * DM;
  const size_t EL3 = (size_t)NT * 6144;
  __bf16* Xb    = (__bf16*)alloc(EL * 2);
  __bf16* Wqkvt = (__bf16*)alloc((size_t)6144 * KD * 2);  // [Wq^T | Wk^T | Wv^T]
  __bf16* W1t   = (__bf16*)alloc((size_t)DM * KD * 2);
  __bf16* W2t   = (__bf16*)alloc((size_t)DM * KD * 2);
  float*  b3    = (float*)alloc(6144 * 4);
  __bf16* QKVb  = (__bf16*)alloc(EL3 * 2);
  __bf16* X1b   = (__bf16*)alloc(EL * 2);
  // fp32 X1 residual if workspace allows; else fall back to bf16 residual
  const int use_f32 = (ws_size >= off + EL * 4) ? 1 : 0;
  float* X1 = nullptr;
  if (use_f32) X1 = (float*)alloc(EL * 4);
  __bf16* Hb = Xb;            // h reuses Xb (dead after QKV GEMM)
  float*  Z  = (float*)QKVb;  // Z (fp32, 128MB) reuses QKVb (192MB, dead after attn)

  k_cast<<<dim3(NT * DM / 2048), dim3(256), 0, stream>>>(X, Xb);
  dim3 tb(32, 8), tg(64, 64);
  k_transpose<<<tg, tb, 0, stream>>>(Wq, Wqkvt);
  k_transpose<<<tg, tb, 0, stream>>>(Wk, Wqkvt + (size_t)2048 * KD);
  k_transpose<<<tg, tb, 0, stream>>>(Wv, Wqkvt + (size_t)4096 * KD);
  k_transpose<<<tg, tb, 0, stream>>>(W1, W1t);
  k_transpose<<<tg, tb, 0, stream>>>(W2, W2t);
  k_bias3<<<dim3(24), dim3(256), 0, stream>>>(bq, bk, bv, b3);

  // fused QKV GEMM: M=16384, N=6144
  k_gemm<<<dim3((NT / 128) * 48), dim3(256), 0, stream>>>(
      Xb, Wqkvt, b3, 0, 48, 6144, QKVb, nullptr, nullptr, nullptr);
  k_attn_ln1<<<dim3(NT), dim3(256), 0, stream>>>(QKVb, X, g1, be1, X1, X1b, use_f32);
  // FFN1 (+GELU): M=16384, N=2048
  k_gemm<<<dim3((NT / 128) * 16), dim3(256), 0, stream>>>(
      X1b, W1t, b1, 1, 16, 2048, Hb, nullptr, nullptr, nullptr);
  // FFN2 (+bias +residual, fp32 out)
  k_gemm<<<dim3((NT / 128) * 16), dim3(256), 0, stream>>>(
      Hb, W2t, b2, use_f32 ? 2 : 3, 16, 2048, nullptr, X1, X1b, Z);
  k_ln2<<<dim3(NT), dim3(256), 0, stream>>>(Z, g2, be2, out);
}

// Round 3
// 1355.757 us; speedup vs baseline: 1.0418x; 1.0191x over previous
//
#include <hip/hip_runtime.h>
#include <math.h>

#define DM 2048      // model dim
#define NT 16384     // tokens = B*S
#define KD 2048      // GEMM K

typedef __bf16 bf16x8 __attribute__((ext_vector_type(8)));
typedef float  f32x4  __attribute__((ext_vector_type(4)));

__device__ __forceinline__ void gld_lds16(const void* g, void* l) {
  __builtin_amdgcn_global_load_lds(
      (const __attribute__((address_space(1))) unsigned int*)g,
      (__attribute__((address_space(3))) unsigned int*)l, 16, 0, 0);
}

// ---------------- cast fp32 -> bf16 (vectorized) ----------------
__global__ __launch_bounds__(256) void k_cast(const float* __restrict__ x,
                                              __bf16* __restrict__ y) {
  const size_t i = ((size_t)blockIdx.x * 256 + threadIdx.x) * 8;
  const float4 a = *(const float4*)(x + i);
  const float4 b = *(const float4*)(x + i + 4);
  bf16x8 o;
  o[0]=(__bf16)a.x; o[1]=(__bf16)a.y; o[2]=(__bf16)a.z; o[3]=(__bf16)a.w;
  o[4]=(__bf16)b.x; o[5]=(__bf16)b.y; o[6]=(__bf16)b.z; o[7]=(__bf16)b.w;
  *(bf16x8*)(y + i) = o;
}

// -------- transpose+cast: W (KDxN fp32 row-major, N=2048) -> Wt (N x KD bf16) --------
__global__ __launch_bounds__(256) void k_transpose(const float* __restrict__ W,
                                                   __bf16* __restrict__ Wt) {
  __shared__ float t[32][33];
  const int tx = threadIdx.x, ty = threadIdx.y;
  const int n  = blockIdx.x * 32 + tx;
  const int k0 = blockIdx.y * 32;
  #pragma unroll
  for (int j = 0; j < 32; j += 8) t[ty + j][tx] = W[(size_t)(k0 + ty + j) * DM + n];
  __syncthreads();
  const int kk = k0 + tx;
  const int n0 = blockIdx.x * 32;
  #pragma unroll
  for (int j = 0; j < 32; j += 8)
    Wt[(size_t)(n0 + ty + j) * KD + kk] = (__bf16)t[tx][ty + j];
}

// -------- concat 3 bias vectors (2048 each) into one 6144 --------
__global__ __launch_bounds__(256) void k_bias3(const float* __restrict__ a,
                                               const float* __restrict__ b,
                                               const float* __restrict__ c,
                                               float* __restrict__ o) {
  const int i = blockIdx.x * 256 + threadIdx.x;
  o[i] = (i < 2048) ? a[i] : ((i < 4096) ? b[i - 2048] : c[i - 4096]);
}

// ---------------- bf16 MFMA GEMM, m97 structure + N-fastest swizzle ----------------
// A: M x KD bf16 row-major.  Bt: N x KD bf16 row-major (B transposed).
// LDS layout XOR-swizzled per row-pair: block b of row r holds global col-block
// b ^ ((r>>1)&3). Breaks the 8-way bank aliasing of the fragment ds_read_b128
// (each (row-parity, block) combo -> exactly 2 lanes = free 2-way).
// mode 0: out = bf16(acc + bias)                      -> outb (LDS-coalesced stores)
// mode 1: out = bf16(gelu(acc + bias))                -> outb (LDS-coalesced stores)
// mode 2: out = acc + bias + resf (fp32 residual)     -> outf
// mode 3: out = acc + bias + resb (bf16 residual)     -> outf
__global__ __launch_bounds__(256, 2) void k_gemm(
    const __bf16* __restrict__ A, const __bf16* __restrict__ Bt,
    const float* __restrict__ bias, const int mode, const int ntile_n,
    const int NS,
    __bf16* __restrict__ outb, const float* __restrict__ resf,
    const __bf16* __restrict__ resb, float* __restrict__ outf) {
  __shared__ __bf16 As[128 * 32];
  __shared__ __bf16 Bs[128 * 32];
  const int tid  = threadIdx.x;
  const int wave = tid >> 6, lane = tid & 63;
  const int quad = lane >> 4, r16 = lane & 15;
  const int bid = blockIdx.x;
  const int m0 = (bid / ntile_n) * 128;
  const int n0 = (bid % ntile_n) * 128;
  const int wm = (wave >> 1) * 64, wn = (wave & 1) * 64;

  // staging: lane order == LDS order (global_load_lds is wave-uniform base + lane*16)
  // XOR swizzle: lane (srow, tid&3) fetches global col-block (tid&3)^((srow>>1)&3)
  // (4-lane groups still cover one contiguous 64B segment -> coalescing intact)
  const int srow = tid >> 2;
  const int scol = (((tid & 3) ^ ((srow >> 1) & 3))) * 8;
  const __bf16* Ap0 = A  + (size_t)(m0 + srow) * KD + scol;
  const __bf16* Ap1 = A  + (size_t)(m0 + 64 + srow) * KD + scol;
  const __bf16* Bp0 = Bt + (size_t)(n0 + srow) * KD + scol;
  const __bf16* Bp1 = Bt + (size_t)(n0 + 64 + srow) * KD + scol;
  __bf16* AsW0 = &As[wave * 512];
  __bf16* AsW1 = &As[2048 + wave * 512];
  __bf16* BsW0 = &Bs[wave * 512];
  __bf16* BsW1 = &Bs[2048 + wave * 512];

  // fragment read: global block `quad` of row r lives at LDS block quad^((r>>1)&3);
  // rows differ only in r16 within a 16-group -> lane-constant block index
  const int rblk = (quad ^ ((r16 >> 1) & 3)) * 8;

  f32x4 acc[4][4] = {};

  for (int k0 = 0; k0 < KD; k0 += 32) {
    gld_lds16(Ap0 + k0, AsW0);
    gld_lds16(Ap1 + k0, AsW1);
    gld_lds16(Bp0 + k0, BsW0);
    gld_lds16(Bp1 + k0, BsW1);
    __syncthreads();
    bf16x8 af[4], bfr[4];
    #pragma unroll
    for (int mi = 0; mi < 4; mi++)
      af[mi] = *(const bf16x8*)&As[(wm + mi * 16 + r16) * 32 + rblk];
    #pragma unroll
    for (int ni = 0; ni < 4; ni++)
      bfr[ni] = *(const bf16x8*)&Bs[(wn + ni * 16 + r16) * 32 + rblk];
    #pragma unroll
    for (int mi = 0; mi < 4; mi++)
      #pragma unroll
      for (int ni = 0; ni < 4; ni++)
        acc[mi][ni] = __builtin_amdgcn_mfma_f32_16x16x32_bf16(af[mi], bfr[ni], acc[mi][ni], 0, 0, 0);
    __syncthreads();
  }

  // epilogue: C/D layout col=lane&15, row=(lane>>4)*4+reg
  if (mode <= 1) {
    // bf16 out: transpose through per-wave LDS chunk (As/Bs dead after last sync)
    // -> 16B/lane fully-coalesced global stores (kills write amplification)
    __bf16* eb = (wave < 2) ? &As[wave * 2048] : &Bs[(wave - 2) * 2048];  // 64x32 bf16
    #pragma unroll
    for (int half = 0; half < 2; half++) {
      #pragma unroll
      for (int nj = 0; nj < 2; nj++) {
        const int ni = half * 2 + nj;
        const int gn = n0 + wn + ni * 16 + r16;
        const float bv = bias[gn];
        #pragma unroll
        for (int mi = 0; mi < 4; mi++) {
          #pragma unroll
          for (int r = 0; r < 4; r++) {
            float v = acc[mi][ni][r] + bv;
            if (mode == 1) v = 0.5f * v * (1.0f + erff(v * 0.70710678118654752f));
            eb[(mi * 16 + quad * 4 + r) * 32 + nj * 16 + r16] = (__bf16)v;
          }
        }
      }
      // same-wave LDS write->read: compiler inserts lgkmcnt waits; no barrier needed
      #pragma unroll
      for (int rd = 0; rd < 4; rd++) {
        const int row = rd * 16 + (lane >> 2);
        const int c0 = (lane & 3) * 8;
        bf16x8 vv = *(const bf16x8*)&eb[row * 32 + c0];
        *(bf16x8*)(outb + (size_t)(m0 + wm + row) * NS + n0 + wn + half * 32 + c0) = vv;
      }
    }
  } else {
    // fp32 out (+residual): 16 lanes x 4B = full 64B lines already
    #pragma unroll
    for (int ni = 0; ni < 4; ni++) {
      const int gn = n0 + wn + ni * 16 + r16;
      const float bv = bias[gn];
      #pragma unroll
      for (int mi = 0; mi < 4; mi++) {
        const int gm = m0 + wm + mi * 16 + quad * 4;
        if (mode == 2) {
          #pragma unroll
          for (int r = 0; r < 4; r++) {
            const size_t o = (size_t)(gm + r) * NS + gn;
            outf[o] = acc[mi][ni][r] + bv + resf[o];
          }
        } else {
          #pragma unroll
          for (int r = 0; r < 4; r++) {
            const size_t o = (size_t)(gm + r) * NS + gn;
            outf[o] = acc[mi][ni][r] + bv + (float)resb[o];
          }
        }
      }
    }
  }
}

// -------- per-token head-attention + residual + LN1 (one block per token) --------
// QKV: NT x 6144 bf16 (q | k | v per token row)
__global__ __launch_bounds__(256) void k_attn_ln1(
    const __bf16* __restrict__ QKV, const float* __restrict__ X,
    const float* __restrict__ g1, const float* __restrict__ be1,
    float* __restrict__ X1, __bf16* __restrict__ X1b, const int use_f32) {
  __shared__ float qs[16 * 132];  // stride 132 breaks 16-way bank conflicts
  __shared__ float ks[16 * 132];
  __shared__ float vs[16 * 132];
  __shared__ float p[256];
  __shared__ float red[8];
  const int tid = threadIdx.x;
  const size_t qbase = (size_t)blockIdx.x * 6144;
  const size_t base  = (size_t)blockIdx.x * DM;
  const int e0 = tid * 8;

  {  // load q,k,v rows -> LDS fp32
    const int row = e0 >> 7, c0 = e0 & 127;
    bf16x8 qv = *(const bf16x8*)(QKV + qbase + e0);
    bf16x8 kv = *(const bf16x8*)(QKV + qbase + 2048 + e0);
    bf16x8 vv = *(const bf16x8*)(QKV + qbase + 4096 + e0);
    #pragma unroll
    for (int j = 0; j < 8; j++) {
      qs[row * 132 + c0 + j] = (float)qv[j];
      ks[row * 132 + c0 + j] = (float)kv[j];
      vs[row * 132 + c0 + j] = (float)vv[j];
    }
  }
  __syncthreads();

  {  // scores + softmax over t (16 lanes per head)
    const int h = tid >> 4, t = tid & 15;
    const float* qp = &qs[h * 132];
    const float* kp = &ks[t * 132];
    float s = 0.f;
    #pragma unroll
    for (int d = 0; d < 128; d++) s += qp[d] * kp[d];
    s *= 0.08838834764831845f;  // 1/sqrt(128)
    float mx = s;
    #pragma unroll
    for (int off = 8; off; off >>= 1) mx = fmaxf(mx, __shfl_xor(mx, off, 16));
    const float e = expf(s - mx);
    float sum = e;
    #pragma unroll
    for (int off = 8; off; off >>= 1) sum += __shfl_xor(sum, off, 16);
    p[tid] = e / sum;
  }
  __syncthreads();

  // y = att @ v ; z = X + y ; LN partials
  float zloc[8];
  float zs = 0.f, zq = 0.f;
  {
    const float4 x1 = *(const float4*)(X + base + e0);
    const float4 x2 = *(const float4*)(X + base + e0 + 4);
    const float xr[8] = {x1.x, x1.y, x1.z, x1.w, x2.x, x2.y, x2.z, x2.w};
    const int hh = e0 >> 7;
    const int d0 = e0 & 127;
    const float* pp = &p[hh * 16];
    #pragma unroll
    for (int j = 0; j < 8; j++) {
      float y = 0.f;
      #pragma unroll
      for (int t2 = 0; t2 < 16; t2++) y += pp[t2] * vs[t2 * 132 + d0 + j];
      const float z = xr[j] + y;
      zloc[j] = z; zs += z; zq += z * z;
    }
  }
  #pragma unroll
  for (int off = 32; off; off >>= 1) {
    zs += __shfl_xor(zs, off, 64);
    zq += __shfl_xor(zq, off, 64);
  }
  const int wave = tid >> 6, lane = tid & 63;
  if (lane == 0) { red[wave] = zs; red[4 + wave] = zq; }
  __syncthreads();
  zs = red[0] + red[1] + red[2] + red[3];
  zq = red[4] + red[5] + red[6] + red[7];
  const float mean = zs * (1.f / DM);
  const float var = zq * (1.f / DM) - mean * mean;
  const float rstd = rsqrtf(var + 1e-5f);
  {
    float o[8];
    #pragma unroll
    for (int j = 0; j < 8; j++)
      o[j] = (zloc[j] - mean) * rstd * g1[e0 + j] + be1[e0 + j];
    if (use_f32) {
      *(float4*)(X1 + base + e0)     = make_float4(o[0], o[1], o[2], o[3]);
      *(float4*)(X1 + base + e0 + 4) = make_float4(o[4], o[5], o[6], o[7]);
    }
    bf16x8 ob;
    #pragma unroll
    for (int j = 0; j < 8; j++) ob[j] = (__bf16)o[j];
    *(bf16x8*)(X1b + base + e0) = ob;
  }
}

// ---------------- final LN2 (one block per token) ----------------
__global__ __launch_bounds__(256) void k_ln2(const float* __restrict__ Z,
                                             const float* __restrict__ g,
                                             const float* __restrict__ be,
                                             float* __restrict__ out) {
  __shared__ float red[8];
  const int tid = threadIdx.x;
  const size_t base = (size_t)blockIdx.x * DM;
  const int e0 = tid * 8;
  const float4 a = *(const float4*)(Z + base + e0);
  const float4 b = *(const float4*)(Z + base + e0 + 4);
  float z[8] = {a.x, a.y, a.z, a.w, b.x, b.y, b.z, b.w};
  float zs = 0.f, zq = 0.f;
  #pragma unroll
  for (int j = 0; j < 8; j++) { zs += z[j]; zq += z[j] * z[j]; }
  #pragma unroll
  for (int off = 32; off; off >>= 1) {
    zs += __shfl_xor(zs, off, 64);
    zq += __shfl_xor(zq, off, 64);
  }
  const int wave = tid >> 6, lane = tid & 63;
  if (lane == 0) { red[wave] = zs; red[4 + wave] = zq; }
  __syncthreads();
  zs = red[0] + red[1] + red[2] + red[3];
  zq = red[4] + red[5] + red[6] + red[7];
  const float mean = zs * (1.f / DM);
  const float var = zq * (1.f / DM) - mean * mean;
  const float rstd = rsqrtf(var + 1e-5f);
  float o[8];
  #pragma unroll
  for (int j = 0; j < 8; j++)
    o[j] = (z[j] - mean) * rstd * g[e0 + j] + be[e0 + j];
  *(float4*)(out + base + e0)     = make_float4(o[0], o[1], o[2], o[3]);
  *(float4*)(out + base + e0 + 4) = make_float4(o[4], o[5], o[6], o[7]);
}

extern "C" void kernel_launch(void* const* d_in, const int* in_sizes, int n_in,
                              void* d_out, int out_size, void* d_ws, size_t ws_size,
                              hipStream_t stream) {
  const float* X   = (const float*)d_in[0];
  const float* Wq  = (const float*)d_in[1];
  const float* bq  = (const float*)d_in[2];
  const float* Wk  = (const float*)d_in[3];
  const float* bk  = (const float*)d_in[4];
  const float* Wv  = (const float*)d_in[5];
  const float* bv  = (const float*)d_in[6];
  const float* g1  = (const float*)d_in[7];
  const float* be1 = (const float*)d_in[8];
  const float* W1  = (const float*)d_in[9];
  const float* b1  = (const float*)d_in[10];
  const float* W2  = (const float*)d_in[11];
  const float* b2  = (const float*)d_in[12];
  const float* g2  = (const float*)d_in[13];
  const float* be2 = (const float*)d_in[14];
  float* out = (float*)d_out;

  char* ws = (char*)d_ws;
  size_t off = 0;
  auto alloc = [&](size_t b) -> char* {
    char* p = ws + off;
    off += (b + 255) & ~(size_t)255;
    return p;
  };
  const size_t EL  = (size_t)NT * DM;
  const size_t EL3 = (size_t)NT * 6144;
  __bf16* Xb    = (__bf16*)alloc(EL * 2);
  __bf16* Wqkvt = (__bf16*)alloc((size_t)6144 * KD * 2);  // [Wq^T | Wk^T | Wv^T]
  __bf16* W1t   = (__bf16*)alloc((size_t)DM * KD * 2);
  __bf16* W2t   = (__bf16*)alloc((size_t)DM * KD * 2);
  float*  b3    = (float*)alloc(6144 * 4);
  __bf16* QKVb  = (__bf16*)alloc(EL3 * 2);
  __bf16* X1b   = (__bf16*)alloc(EL * 2);
  // fp32 X1 residual if workspace allows; else fall back to bf16 residual
  const int use_f32 = (ws_size >= off + EL * 4) ? 1 : 0;
  float* X1 = nullptr;
  if (use_f32) X1 = (float*)alloc(EL * 4);
  __bf16* Hb = Xb;            // h reuses Xb (dead after QKV GEMM)
  float*  Z  = (float*)QKVb;  // Z (fp32, 128MB) reuses QKVb (192MB, dead after attn)

  k_cast<<<dim3(NT * DM / 2048), dim3(256), 0, stream>>>(X, Xb);
  dim3 tb(32, 8), tg(64, 64);
  k_transpose<<<tg, tb, 0, stream>>>(Wq, Wqkvt);
  k_transpose<<<tg, tb, 0, stream>>>(Wk, Wqkvt + (size_t)2048 * KD);
  k_transpose<<<tg, tb, 0, stream>>>(Wv, Wqkvt + (size_t)4096 * KD);
  k_transpose<<<tg, tb, 0, stream>>>(W1, W1t);
  k_transpose<<<tg, tb, 0, stream>>>(W2, W2t);
  k_bias3<<<dim3(24), dim3(256), 0, stream>>>(bq, bk, bv, b3);

  // fused QKV GEMM: M=16384, N=6144
  k_gemm<<<dim3((NT / 128) * 48), dim3(256), 0, stream>>>(
      Xb, Wqkvt, b3, 0, 48, 6144, QKVb, nullptr, nullptr, nullptr);
  k_attn_ln1<<<dim3(NT), dim3(256), 0, stream>>>(QKVb, X, g1, be1, X1, X1b, use_f32);
  // FFN1 (+GELU): M=16384, N=2048
  k_gemm<<<dim3((NT / 128) * 16), dim3(256), 0, stream>>>(
      X1b, W1t, b1, 1, 16, 2048, Hb, nullptr, nullptr, nullptr);
  // FFN2 (+bias +residual, fp32 out)
  k_gemm<<<dim3((NT / 128) * 16), dim3(256), 0, stream>>>(
      Hb, W2t, b2, use_f32 ? 2 : 3, 16, 2048, nullptr, X1, X1b, Z);
  k_ln2<<<dim3(NT), dim3(256), 0, stream>>>(Z, g2, be2, out);
}

// Round 4
// 1231.322 us; speedup vs baseline: 1.1471x; 1.1011x over previous
//
#include <hip/hip_runtime.h>
#include <math.h>

#define DM 2048      // model dim
#define NT 16384     // tokens = B*S
#define KD 2048      // GEMM K

typedef __bf16 bf16x8 __attribute__((ext_vector_type(8)));
typedef float  f32x4  __attribute__((ext_vector_type(4)));

__device__ __forceinline__ void gld_lds16(const void* g, void* l) {
  __builtin_amdgcn_global_load_lds(
      (const __attribute__((address_space(1))) unsigned int*)g,
      (__attribute__((address_space(3))) unsigned int*)l, 16, 0, 0);
}

// ---------------- cast fp32 -> bf16 (vectorized) ----------------
__global__ __launch_bounds__(256) void k_cast(const float* __restrict__ x,
                                              __bf16* __restrict__ y) {
  const size_t i = ((size_t)blockIdx.x * 256 + threadIdx.x) * 8;
  const float4 a = *(const float4*)(x + i);
  const float4 b = *(const float4*)(x + i + 4);
  bf16x8 o;
  o[0]=(__bf16)a.x; o[1]=(__bf16)a.y; o[2]=(__bf16)a.z; o[3]=(__bf16)a.w;
  o[4]=(__bf16)b.x; o[5]=(__bf16)b.y; o[6]=(__bf16)b.z; o[7]=(__bf16)b.w;
  *(bf16x8*)(y + i) = o;
}

// -------- transpose+cast: W (KDxN fp32 row-major, N=2048) -> Wt (N x KD bf16) --------
__global__ __launch_bounds__(256) void k_transpose(const float* __restrict__ W,
                                                   __bf16* __restrict__ Wt) {
  __shared__ float t[32][33];
  const int tx = threadIdx.x, ty = threadIdx.y;
  const int n  = blockIdx.x * 32 + tx;
  const int k0 = blockIdx.y * 32;
  #pragma unroll
  for (int j = 0; j < 32; j += 8) t[ty + j][tx] = W[(size_t)(k0 + ty + j) * DM + n];
  __syncthreads();
  const int kk = k0 + tx;
  const int n0 = blockIdx.x * 32;
  #pragma unroll
  for (int j = 0; j < 32; j += 8)
    Wt[(size_t)(n0 + ty + j) * KD + kk] = (__bf16)t[tx][ty + j];
}

// -------- concat 3 bias vectors (2048 each) into one 6144 --------
__global__ __launch_bounds__(256) void k_bias3(const float* __restrict__ a,
                                               const float* __restrict__ b,
                                               const float* __restrict__ c,
                                               float* __restrict__ o) {
  const int i = blockIdx.x * 256 + threadIdx.x;
  o[i] = (i < 2048) ? a[i] : ((i < 4096) ? b[i - 2048] : c[i - 4096]);
}

// ---------------- bf16 MFMA GEMM: BK=64, 32 MFMA per barrier-pair ----------------
// A: M x KD bf16 row-major.  Bt: N x KD bf16 row-major (B transposed).
// 1-D grid, bid -> (mt = bid/ntile_n, nt = bid%ntile_n): N fastest for L2/L3 reuse.
// LDS 128x64 per matrix, XOR swizzle: col-block b (16B) of row r stored at block
// b ^ (r&7) -> fragment ds_read_b128 spreads over all 32 banks (<=2-way, free).
// BK=64 halves the __syncthreads count vs BK=32 (the vmcnt(0) drain at each
// barrier was ~47% of cycles at BK=32) at 32 KB LDS (still 5 blocks/CU max).
// mode 0: out = bf16(acc + bias)                      -> outb (LDS-coalesced stores)
// mode 1: out = bf16(gelu(acc + bias))                -> outb (LDS-coalesced stores)
// mode 2: out = acc + bias + resf (fp32 residual)     -> outf
// mode 3: out = acc + bias + resb (bf16 residual)     -> outf
__global__ __launch_bounds__(256, 2) void k_gemm(
    const __bf16* __restrict__ A, const __bf16* __restrict__ Bt,
    const float* __restrict__ bias, const int mode, const int ntile_n,
    const int NS,
    __bf16* __restrict__ outb, const float* __restrict__ resf,
    const __bf16* __restrict__ resb, float* __restrict__ outf) {
  __shared__ __bf16 As[128 * 64];
  __shared__ __bf16 Bs[128 * 64];
  const int tid  = threadIdx.x;
  const int wave = tid >> 6, lane = tid & 63;
  const int quad = lane >> 4, r16 = lane & 15;
  const int bid = blockIdx.x;
  const int m0 = (bid / ntile_n) * 128;
  const int n0 = (bid % ntile_n) * 128;
  const int wm = (wave >> 1) * 64, wn = (wave & 1) * 64;

  // staging: 8 lanes cover one 128B row-slice; lane l -> row lrow, LDS block l&7
  // holding global block (l&7)^lrow (8-lane group still covers a contiguous
  // 128B global span -> coalescing intact)
  const int lrow = lane >> 3;
  const int gblk = (lane & 7) ^ lrow;
  const __bf16* Ap[4];
  const __bf16* Bp[4];
  __bf16* AsW[4];
  __bf16* BsW[4];
  #pragma unroll
  for (int i = 0; i < 4; i++) {
    const int sr = i * 32 + wave * 8 + lrow;   // sr&7 == lrow
    Ap[i] = A  + (size_t)(m0 + sr) * KD + gblk * 8;
    Bp[i] = Bt + (size_t)(n0 + sr) * KD + gblk * 8;
    AsW[i] = &As[i * 2048 + wave * 512];
    BsW[i] = &Bs[i * 2048 + wave * 512];
  }

  f32x4 acc[4][4] = {};

  for (int k0 = 0; k0 < KD; k0 += 64) {
    #pragma unroll
    for (int i = 0; i < 4; i++) {
      gld_lds16(Ap[i] + k0, AsW[i]);
      gld_lds16(Bp[i] + k0, BsW[i]);
    }
    __syncthreads();
    #pragma unroll
    for (int ks = 0; ks < 2; ks++) {
      // global block ks*4+quad of row r lives at LDS block (ks*4+quad)^(r&7);
      // fragment rows differ only in r16 -> r&7 == r16&7
      const int fb = ((ks * 4 + quad) ^ (r16 & 7)) * 8;
      bf16x8 af[4], bfr[4];
      #pragma unroll
      for (int mi = 0; mi < 4; mi++)
        af[mi] = *(const bf16x8*)&As[(wm + mi * 16 + r16) * 64 + fb];
      #pragma unroll
      for (int ni = 0; ni < 4; ni++)
        bfr[ni] = *(const bf16x8*)&Bs[(wn + ni * 16 + r16) * 64 + fb];
      #pragma unroll
      for (int mi = 0; mi < 4; mi++)
        #pragma unroll
        for (int ni = 0; ni < 4; ni++)
          acc[mi][ni] = __builtin_amdgcn_mfma_f32_16x16x32_bf16(af[mi], bfr[ni], acc[mi][ni], 0, 0, 0);
    }
    __syncthreads();
  }

  // epilogue: C/D layout col=lane&15, row=(lane>>4)*4+reg
  if (mode <= 1) {
    // bf16 out: transpose through per-wave LDS chunk (As dead after last sync)
    // -> 16B/lane fully-coalesced global stores
    __bf16* eb = &As[wave * 2048];  // 64x32 bf16 private chunk
    #pragma unroll
    for (int half = 0; half < 2; half++) {
      #pragma unroll
      for (int nj = 0; nj < 2; nj++) {
        const int ni = half * 2 + nj;
        const int gn = n0 + wn + ni * 16 + r16;
        const float bv = bias[gn];
        #pragma unroll
        for (int mi = 0; mi < 4; mi++) {
          #pragma unroll
          for (int r = 0; r < 4; r++) {
            float v = acc[mi][ni][r] + bv;
            if (mode == 1) v = 0.5f * v * (1.0f + erff(v * 0.70710678118654752f));
            eb[(mi * 16 + quad * 4 + r) * 32 + nj * 16 + r16] = (__bf16)v;
          }
        }
      }
      // same-wave LDS write->read: compiler inserts lgkmcnt waits; no barrier needed
      #pragma unroll
      for (int rd = 0; rd < 4; rd++) {
        const int row = rd * 16 + (lane >> 2);
        const int c0 = (lane & 3) * 8;
        bf16x8 vv = *(const bf16x8*)&eb[row * 32 + c0];
        *(bf16x8*)(outb + (size_t)(m0 + wm + row) * NS + n0 + wn + half * 32 + c0) = vv;
      }
    }
  } else {
    // fp32 out (+residual): 16 lanes x 4B = full 64B lines already
    #pragma unroll
    for (int ni = 0; ni < 4; ni++) {
      const int gn = n0 + wn + ni * 16 + r16;
      const float bv = bias[gn];
      #pragma unroll
      for (int mi = 0; mi < 4; mi++) {
        const int gm = m0 + wm + mi * 16 + quad * 4;
        if (mode == 2) {
          #pragma unroll
          for (int r = 0; r < 4; r++) {
            const size_t o = (size_t)(gm + r) * NS + gn;
            outf[o] = acc[mi][ni][r] + bv + resf[o];
          }
        } else {
          #pragma unroll
          for (int r = 0; r < 4; r++) {
            const size_t o = (size_t)(gm + r) * NS + gn;
            outf[o] = acc[mi][ni][r] + bv + (float)resb[o];
          }
        }
      }
    }
  }
}

// -------- per-token head-attention + residual + LN1 (one block per token) --------
// QKV: NT x 6144 bf16 (q | k | v per token row)
__global__ __launch_bounds__(256) void k_attn_ln1(
    const __bf16* __restrict__ QKV, const float* __restrict__ X,
    const float* __restrict__ g1, const float* __restrict__ be1,
    float* __restrict__ X1, __bf16* __restrict__ X1b, const int use_f32) {
  __shared__ float qs[16 * 132];  // stride 132 breaks 16-way bank conflicts
  __shared__ float ks[16 * 132];
  __shared__ float vs[16 * 132];
  __shared__ float p[256];
  __shared__ float red[8];
  const int tid = threadIdx.x;
  const size_t qbase = (size_t)blockIdx.x * 6144;
  const size_t base  = (size_t)blockIdx.x * DM;
  const int e0 = tid * 8;

  {  // load q,k,v rows -> LDS fp32
    const int row = e0 >> 7, c0 = e0 & 127;
    bf16x8 qv = *(const bf16x8*)(QKV + qbase + e0);
    bf16x8 kv = *(const bf16x8*)(QKV + qbase + 2048 + e0);
    bf16x8 vv = *(const bf16x8*)(QKV + qbase + 4096 + e0);
    #pragma unroll
    for (int j = 0; j < 8; j++) {
      qs[row * 132 + c0 + j] = (float)qv[j];
      ks[row * 132 + c0 + j] = (float)kv[j];
      vs[row * 132 + c0 + j] = (float)vv[j];
    }
  }
  __syncthreads();

  {  // scores + softmax over t (16 lanes per head)
    const int h = tid >> 4, t = tid & 15;
    const float* qp = &qs[h * 132];
    const float* kp = &ks[t * 132];
    float s = 0.f;
    #pragma unroll
    for (int d = 0; d < 128; d++) s += qp[d] * kp[d];
    s *= 0.08838834764831845f;  // 1/sqrt(128)
    float mx = s;
    #pragma unroll
    for (int off = 8; off; off >>= 1) mx = fmaxf(mx, __shfl_xor(mx, off, 16));
    const float e = expf(s - mx);
    float sum = e;
    #pragma unroll
    for (int off = 8; off; off >>= 1) sum += __shfl_xor(sum, off, 16);
    p[tid] = e / sum;
  }
  __syncthreads();

  // y = att @ v ; z = X + y ; LN partials
  float zloc[8];
  float zs = 0.f, zq = 0.f;
  {
    const float4 x1 = *(const float4*)(X + base + e0);
    const float4 x2 = *(const float4*)(X + base + e0 + 4);
    const float xr[8] = {x1.x, x1.y, x1.z, x1.w, x2.x, x2.y, x2.z, x2.w};
    const int hh = e0 >> 7;
    const int d0 = e0 & 127;
    const float* pp = &p[hh * 16];
    #pragma unroll
    for (int j = 0; j < 8; j++) {
      float y = 0.f;
      #pragma unroll
      for (int t2 = 0; t2 < 16; t2++) y += pp[t2] * vs[t2 * 132 + d0 + j];
      const float z = xr[j] + y;
      zloc[j] = z; zs += z; zq += z * z;
    }
  }
  #pragma unroll
  for (int off = 32; off; off >>= 1) {
    zs += __shfl_xor(zs, off, 64);
    zq += __shfl_xor(zq, off, 64);
  }
  const int wave = tid >> 6, lane = tid & 63;
  if (lane == 0) { red[wave] = zs; red[4 + wave] = zq; }
  __syncthreads();
  zs = red[0] + red[1] + red[2] + red[3];
  zq = red[4] + red[5] + red[6] + red[7];
  const float mean = zs * (1.f / DM);
  const float var = zq * (1.f / DM) - mean * mean;
  const float rstd = rsqrtf(var + 1e-5f);
  {
    float o[8];
    #pragma unroll
    for (int j = 0; j < 8; j++)
      o[j] = (zloc[j] - mean) * rstd * g1[e0 + j] + be1[e0 + j];
    if (use_f32) {
      *(float4*)(X1 + base + e0)     = make_float4(o[0], o[1], o[2], o[3]);
      *(float4*)(X1 + base + e0 + 4) = make_float4(o[4], o[5], o[6], o[7]);
    }
    bf16x8 ob;
    #pragma unroll
    for (int j = 0; j < 8; j++) ob[j] = (__bf16)o[j];
    *(bf16x8*)(X1b + base + e0) = ob;
  }
}

// ---------------- final LN2 (one block per token) ----------------
__global__ __launch_bounds__(256) void k_ln2(const float* __restrict__ Z,
                                             const float* __restrict__ g,
                                             const float* __restrict__ be,
                                             float* __restrict__ out) {
  __shared__ float red[8];
  const int tid = threadIdx.x;
  const size_t base = (size_t)blockIdx.x * DM;
  const int e0 = tid * 8;
  const float4 a = *(const float4*)(Z + base + e0);
  const float4 b = *(const float4*)(Z + base + e0 + 4);
  float z[8] = {a.x, a.y, a.z, a.w, b.x, b.y, b.z, b.w};
  float zs = 0.f, zq = 0.f;
  #pragma unroll
  for (int j = 0; j < 8; j++) { zs += z[j]; zq += z[j] * z[j]; }
  #pragma unroll
  for (int off = 32; off; off >>= 1) {
    zs += __shfl_xor(zs, off, 64);
    zq += __shfl_xor(zq, off, 64);
  }
  const int wave = tid >> 6, lane = tid & 63;
  if (lane == 0) { red[wave] = zs; red[4 + wave] = zq; }
  __syncthreads();
  zs = red[0] + red[1] + red[2] + red[3];
  zq = red[4] + red[5] + red[6] + red[7];
  const float mean = zs * (1.f / DM);
  const float var = zq * (1.f / DM) - mean * mean;
  const float rstd = rsqrtf(var + 1e-5f);
  float o[8];
  #pragma unroll
  for (int j = 0; j < 8; j++)
    o[j] = (z[j] - mean) * rstd * g[e0 + j] + be[e0 + j];
  *(float4*)(out + base + e0)     = make_float4(o[0], o[1], o[2], o[3]);
  *(float4*)(out + base + e0 + 4) = make_float4(o[4], o[5], o[6], o[7]);
}

extern "C" void kernel_launch(void* const* d_in, const int* in_sizes, int n_in,
                              void* d_out, int out_size, void* d_ws, size_t ws_size,
                              hipStream_t stream) {
  const float* X   = (const float*)d_in[0];
  const float* Wq  = (const float*)d_in[1];
  const float* bq  = (const float*)d_in[2];
  const float* Wk  = (const float*)d_in[3];
  const float* bk  = (const float*)d_in[4];
  const float* Wv  = (const float*)d_in[5];
  const float* bv  = (const float*)d_in[6];
  const float* g1  = (const float*)d_in[7];
  const float* be1 = (const float*)d_in[8];
  const float* W1  = (const float*)d_in[9];
  const float* b1  = (const float*)d_in[10];
  const float* W2  = (const float*)d_in[11];
  const float* b2  = (const float*)d_in[12];
  const float* g2  = (const float*)d_in[13];
  const float* be2 = (const float*)d_in[14];
  float* out = (float*)d_out;

  char* ws = (char*)d_ws;
  size_t off = 0;
  auto alloc = [&](size_t b) -> char* {
    char* p = ws + off;
    off += (b + 255) & ~(size_t)255;
    return p;
  };
  const size_t EL  = (size_t)NT * DM;
  const size_t EL3 = (size_t)NT * 6144;
  __bf16* Xb    = (__bf16*)alloc(EL * 2);
  __bf16* Wqkvt = (__bf16*)alloc((size_t)6144 * KD * 2);  // [Wq^T | Wk^T | Wv^T]
  __bf16* W1t   = (__bf16*)alloc((size_t)DM * KD * 2);
  __bf16* W2t   = (__bf16*)alloc((size_t)DM * KD * 2);
  float*  b3    = (float*)alloc(6144 * 4);
  __bf16* QKVb  = (__bf16*)alloc(EL3 * 2);
  __bf16* X1b   = (__bf16*)alloc(EL * 2);
  // fp32 X1 residual if workspace allows; else fall back to bf16 residual
  const int use_f32 = (ws_size >= off + EL * 4) ? 1 : 0;
  float* X1 = nullptr;
  if (use_f32) X1 = (float*)alloc(EL * 4);
  __bf16* Hb = Xb;            // h reuses Xb (dead after QKV GEMM)
  float*  Z  = (float*)QKVb;  // Z (fp32, 128MB) reuses QKVb (192MB, dead after attn)

  k_cast<<<dim3(NT * DM / 2048), dim3(256), 0, stream>>>(X, Xb);
  dim3 tb(32, 8), tg(64, 64);
  k_transpose<<<tg, tb, 0, stream>>>(Wq, Wqkvt);
  k_transpose<<<tg, tb, 0, stream>>>(Wk, Wqkvt + (size_t)2048 * KD);
  k_transpose<<<tg, tb, 0, stream>>>(Wv, Wqkvt + (size_t)4096 * KD);
  k_transpose<<<tg, tb, 0, stream>>>(W1, W1t);
  k_transpose<<<tg, tb, 0, stream>>>(W2, W2t);
  k_bias3<<<dim3(24), dim3(256), 0, stream>>>(bq, bk, bv, b3);

  // fused QKV GEMM: M=16384, N=6144
  k_gemm<<<dim3((NT / 128) * 48), dim3(256), 0, stream>>>(
      Xb, Wqkvt, b3, 0, 48, 6144, QKVb, nullptr, nullptr, nullptr);
  k_attn_ln1<<<dim3(NT), dim3(256), 0, stream>>>(QKVb, X, g1, be1, X1, X1b, use_f32);
  // FFN1 (+GELU): M=16384, N=2048
  k_gemm<<<dim3((NT / 128) * 16), dim3(256), 0, stream>>>(
      X1b, W1t, b1, 1, 16, 2048, Hb, nullptr, nullptr, nullptr);
  // FFN2 (+bias +residual, fp32 out)
  k_gemm<<<dim3((NT / 128) * 16), dim3(256), 0, stream>>>(
      Hb, W2t, b2, use_f32 ? 2 : 3, 16, 2048, nullptr, X1, X1b, Z);
  k_ln2<<<dim3(NT), dim3(256), 0, stream>>>(Z, g2, be2, out);
}